// Round 7
// baseline (1365.785 us; speedup 1.0000x reference)
//
#include <hip/hip_runtime.h>

#define NN 100000     // nodes
#define NE 1600000    // edges before self loops
#define ET 1700000    // NE + NN
#define CH 128        // hidden channels (H*C, H=1)

typedef unsigned int u32;

// ---------------------------------------------------------------------------
// chunk1: out_idx[e] = f32(src), out_idx[ET+e] = f32(dst)
// ---------------------------------------------------------------------------
__global__ __launch_bounds__(256) void k_idx(
    const int* __restrict__ ei, float* __restrict__ out_idx)
{
    int e = blockIdx.x * 256 + threadIdx.x;
    if (e >= ET) return;
    int s, d;
    if (e < NE) { s = ei[e]; d = ei[NE + e]; }
    else        { s = d = e - NE; }
    out_idx[e]      = (float)s;
    out_idx[ET + e] = (float)d;
}

// ---------------------------------------------------------------------------
// CSR build: cnt[dst]++  ->  2-level exclusive scan -> scatter edge ids
// ---------------------------------------------------------------------------
__global__ __launch_bounds__(256) void k_deg(
    const int* __restrict__ ei, u32* __restrict__ cnt)
{
    int e = blockIdx.x * 256 + threadIdx.x;
    if (e >= ET) return;
    int d = (e < NE) ? ei[NE + e] : e - NE;
    if ((u32)d >= NN) d = 0;
    atomicAdd(&cnt[d], 1u);
}

__global__ __launch_bounds__(256) void k_scanA(
    const u32* __restrict__ cnt, u32* __restrict__ bsum)
{
    __shared__ u32 s[256];
    int i = blockIdx.x * 256 + threadIdx.x;
    s[threadIdx.x] = (i < NN) ? cnt[i] : 0u;
    __syncthreads();
    for (int off = 128; off; off >>= 1) {
        if (threadIdx.x < off) s[threadIdx.x] += s[threadIdx.x + off];
        __syncthreads();
    }
    if (threadIdx.x == 0) bsum[blockIdx.x] = s[0];
}

__global__ __launch_bounds__(512) void k_scanB(u32* __restrict__ bsum, int nb)
{
    __shared__ u32 s[512];
    int t = threadIdx.x;
    u32 v = (t < nb) ? bsum[t] : 0u;
    s[t] = v; __syncthreads();
    for (int off = 1; off < 512; off <<= 1) {
        u32 a = (t >= off) ? s[t - off] : 0u;
        __syncthreads();
        s[t] += a;
        __syncthreads();
    }
    if (t < nb) bsum[t] = s[t] - v;    // exclusive block offsets
}

__global__ __launch_bounds__(256) void k_scanC(
    const u32* __restrict__ cnt, const u32* __restrict__ bsum,
    u32* __restrict__ rowptr)
{
    __shared__ u32 s[256];
    int i = blockIdx.x * 256 + threadIdx.x;
    u32 v = (i < NN) ? cnt[i] : 0u;
    s[threadIdx.x] = v; __syncthreads();
    for (int off = 1; off < 256; off <<= 1) {
        u32 a = (threadIdx.x >= off) ? s[threadIdx.x - off] : 0u;
        __syncthreads();
        s[threadIdx.x] += a;
        __syncthreads();
    }
    if (i < NN) rowptr[i] = s[threadIdx.x] - v + bsum[blockIdx.x];
    if (i == 0) rowptr[NN] = ET;
}

__global__ __launch_bounds__(256) void k_scatter(
    const int* __restrict__ ei, const u32* __restrict__ rowptr,
    u32* __restrict__ cnt, u32* __restrict__ eid)
{
    int e = blockIdx.x * 256 + threadIdx.x;
    if (e >= ET) return;
    int d = (e < NE) ? ei[NE + e] : e - NE;
    if ((u32)d >= NN) d = 0;
    u32 pos = rowptr[d] + atomicAdd(&cnt[d], 1u);
    eid[pos] = (u32)e;
}

// ---------------------------------------------------------------------------
// k_pre: xl[n,:] = x[n]@Wl + bl ; xr[n,:] = x[n]@Wr + br
// ---------------------------------------------------------------------------
__global__ __launch_bounds__(256) void k_pre(
    const float* __restrict__ x,
    const float* __restrict__ Wl, const float* __restrict__ bl,
    const float* __restrict__ Wr, const float* __restrict__ br,
    float* __restrict__ xl, float* __restrict__ xr)
{
    __shared__ float sWl[6][CH], sWr[6][CH], sbl[CH], sbr[CH];
    for (int i = threadIdx.x; i < 6 * CH; i += 256) {
        sWl[i / CH][i % CH] = Wl[i];
        sWr[i / CH][i % CH] = Wr[i];
    }
    for (int i = threadIdx.x; i < CH; i += 256) { sbl[i] = bl[i]; sbr[i] = br[i]; }
    __syncthreads();

    int tid = blockIdx.x * 256 + threadIdx.x;   // grid covers NN*CH exactly
    int n = tid >> 7, c = tid & 127;
    float xs[6];
#pragma unroll
    for (int k = 0; k < 6; ++k) xs[k] = x[n * 6 + k];
    float vl = sbl[c], vr = sbr[c];
#pragma unroll
    for (int k = 0; k < 6; ++k) {
        vl += xs[k] * sWl[k][c];
        vr += xs[k] * sWr[k][c];
    }
    xl[tid] = vl;
    xr[tid] = vr;
}

// ---------------------------------------------------------------------------
// k_fused (wave/node, CSR): GATv2 attention + softmax + aggregation.
//   pass1: per edge e: z = xl[src] + xr[n] + ea@We; logit = att.leaky(z);
//          ex = exp(logit); den += ex (register); out_alpha[e] = ex
//   pass2: a = ex/den; h += a*xl[src]; out_alpha[e] = a
//   h[n,:] = relu(h + b_gat) -> written OVER xr[n,:] (row n only read by node n)
// No LDS, no float atomics. den max-shift skipped (logits O(1)).
// ---------------------------------------------------------------------------
__global__ __launch_bounds__(256) void k_fused(
    const u32* __restrict__ rowptr, const u32* __restrict__ eid,
    const int* __restrict__ ei, const float* __restrict__ ew,
    const float* __restrict__ xl,
    const float* __restrict__ We, const float* __restrict__ att,
    const float* __restrict__ bgat,
    float* __restrict__ xr,          // in: xr ; out: h (in place)
    float* __restrict__ out_alpha)
{
    int n = (blockIdx.x << 2) + (threadIdx.x >> 6);   // grid: NN/4 blocks
    int lane = threadIdx.x & 63;
    int c0 = lane * 2;

    // per-lane channel constants (2 channels/lane)
    float we00 = We[c0], we01 = We[c0 + 1];
    float we10 = We[CH + c0], we11 = We[CH + c0 + 1];
    float at0 = att[c0], at1 = att[c0 + 1];

    float2 xrv = ((const float2*)xr)[(size_t)n * 64 + lane];
    u32 p0 = rowptr[n], p1 = rowptr[n + 1];

    // ---- pass 1: exp(logits), den ----
    float den = 0.f;
    for (u32 p = p0; p < p1; ++p) {
        u32 e = eid[p];
        int src; float ea0, ea1;
        if (e < NE) {
            src = ei[e];
            ea0 = ew[2 * e]; ea1 = ew[2 * e + 1];
        } else {
            src = (int)e - NE; ea0 = 0.f; ea1 = 0.f;
        }
        if ((u32)src >= NN) src = 0;
        float2 xlv = ((const float2*)xl)[(size_t)src * 64 + lane];
        float z0 = xlv.x + xrv.x + ea0 * we00 + ea1 * we10;
        float z1 = xlv.y + xrv.y + ea0 * we01 + ea1 * we11;
        z0 = z0 > 0.f ? z0 : 0.2f * z0;
        z1 = z1 > 0.f ? z1 : 0.2f * z1;
        float s = z0 * at0 + z1 * at1;
#pragma unroll
        for (int off = 32; off; off >>= 1) s += __shfl_down(s, off, 64);
        s = __shfl(s, 0, 64);
        s = fminf(fmaxf(s, -60.f), 60.f);
        float ex = __expf(s);
        den += ex;
        if (lane == 0) out_alpha[e] = ex;
    }
    float rden = (den > 1e-30f) ? 1.f / den : 0.f;

    // ---- pass 2: normalize + aggregate ----
    float a0 = 0.f, a1 = 0.f;
    for (u32 p = p0; p < p1; ++p) {
        u32 e = eid[p];
        int src = (e < NE) ? ei[e] : (int)e - NE;
        if ((u32)src >= NN) src = 0;
        float a = out_alpha[e] * rden;
        if (lane == 0) out_alpha[e] = a;
        float2 xlv = ((const float2*)xl)[(size_t)src * 64 + lane];
        a0 += a * xlv.x;
        a1 += a * xlv.y;
    }
    float r0 = a0 + bgat[c0];     r0 = r0 > 0.f ? r0 : 0.f;
    float r1 = a1 + bgat[c0 + 1]; r1 = r1 > 0.f ? r1 : 0.f;
    ((float2*)xr)[(size_t)n * 64 + lane] = make_float2(r0, r1);
}

// ---------------------------------------------------------------------------
// GEMM1: hg = h @ W2.  Thread owns column c: W2[:,c] in 128 VGPRs; h-row
// elements are wave-uniform loads -> pure-FMA inner loop.
// ---------------------------------------------------------------------------
__global__ __launch_bounds__(256, 2) void k_gemm1(
    const float* __restrict__ h, const float* __restrict__ W2,
    float* __restrict__ hg)
{
    int c = threadIdx.x & 127;
    int half = threadIdx.x >> 7;
    float w[CH];
#pragma unroll
    for (int k = 0; k < CH; ++k) w[k] = W2[k * CH + c];
    for (int n = blockIdx.x * 2 + half; n < NN; n += gridDim.x * 2) {
        const float* row = h + (size_t)n * CH;
        float acc = 0.f;
#pragma unroll
        for (int k = 0; k < CH; ++k) acc += row[k] * w[k];
        hg[(size_t)n * CH + c] = acc;
    }
}

// ---------------------------------------------------------------------------
// k_h2_csr (wave/node): h2[n,:] = sum_e alpha_e * hg[src_e,:]
// (norm == alpha: deg = sum(alpha) == 1 identically)
// ---------------------------------------------------------------------------
__global__ __launch_bounds__(256) void k_h2_csr(
    const u32* __restrict__ rowptr, const u32* __restrict__ eid,
    const int* __restrict__ ei, const float* __restrict__ alpha,
    const float* __restrict__ hg, float* __restrict__ h2)
{
    int n = (blockIdx.x << 2) + (threadIdx.x >> 6);
    int lane = threadIdx.x & 63;
    u32 p0 = rowptr[n], p1 = rowptr[n + 1];
    float a0 = 0.f, a1 = 0.f;
    for (u32 p = p0; p < p1; ++p) {
        u32 e = eid[p];
        int src = (e < NE) ? ei[e] : (int)e - NE;
        if ((u32)src >= NN) src = 0;
        float al = alpha[e];
        float2 g = ((const float2*)hg)[(size_t)src * 64 + lane];
        a0 += al * g.x;
        a1 += al * g.y;
    }
    ((float2*)h2)[(size_t)n * 64 + lane] = make_float2(a0, a1);
}

// ---------------------------------------------------------------------------
// K_out: out[n,:] = relu(h2 + b_gcn) @ W3 + b3    (wave per node)
// ---------------------------------------------------------------------------
__global__ __launch_bounds__(256) void k_final(
    const float* __restrict__ h2, const float* __restrict__ bgcn,
    const float* __restrict__ W3, const float* __restrict__ b3,
    float* __restrict__ out)
{
    __shared__ float sW30[CH], sW31[CH], sbg[CH];
    for (int i = threadIdx.x; i < CH; i += 256) {
        sW30[i] = W3[2 * i];
        sW31[i] = W3[2 * i + 1];
        sbg[i]  = bgcn[i];
    }
    __syncthreads();
    int n = (blockIdx.x << 2) + (threadIdx.x >> 6);
    int lane = threadIdx.x & 63;
    float a0 = 0.f, a1 = 0.f;
#pragma unroll
    for (int hh = 0; hh < 2; ++hh) {
        int c = lane + (hh << 6);
        float v = h2[(size_t)n * CH + c] + sbg[c];
        v = v > 0.f ? v : 0.f;
        a0 += v * sW30[c];
        a1 += v * sW31[c];
    }
#pragma unroll
    for (int off = 32; off; off >>= 1) {
        a0 += __shfl_down(a0, off, 64);
        a1 += __shfl_down(a1, off, 64);
    }
    if (lane == 0) {
        out[n * 2]     = a0 + b3[0];
        out[n * 2 + 1] = a1 + b3[1];
    }
}

// ---------------------------------------------------------------------------
extern "C" void kernel_launch(void* const* d_in, const int* in_sizes, int n_in,
                              void* d_out, int out_size, void* d_ws, size_t ws_size,
                              hipStream_t stream)
{
    const float* x    = (const float*)d_in[0];
    const int*   ei   = (const int*)d_in[1];
    const float* ew   = (const float*)d_in[2];
    const float* Wl   = (const float*)d_in[3];
    const float* bl   = (const float*)d_in[4];
    const float* Wr   = (const float*)d_in[5];
    const float* br   = (const float*)d_in[6];
    const float* We   = (const float*)d_in[7];
    const float* att  = (const float*)d_in[8];
    const float* bgat = (const float*)d_in[9];
    const float* W2   = (const float*)d_in[10];
    const float* bgcn = (const float*)d_in[11];
    const float* W3   = (const float*)d_in[12];
    const float* b3   = (const float*)d_in[13];

    float* out       = (float*)d_out;          // chunk0: out [N,2] f32
    float* out_idx   = out + 200000;           // chunk1: stack([src,dst]) [2,ET]
    float* out_alpha = out + 200000 + 2 * ET;  // chunk2: alpha [ET,1]

    // workspace (110.1 MB): XL[NN*CH] | XR[NN*CH] | eid[ET] | cnt[NN] | rowptr[NN+1] | bsum[512]
    // XR becomes h (in k_fused, in place), then h2 (k_h2_csr). hg goes into XL.
    float* XL     = (float*)d_ws;
    float* XR     = XL + (size_t)NN * CH;
    u32*   eid    = (u32*)(XR + (size_t)NN * CH);
    u32*   cnt    = eid + ET;
    u32*   rowptr = cnt + NN;
    u32*   bsum   = rowptr + NN + 1;

    const int EB = (ET + 255) / 256;
    const int SB = (NN + 255) / 256;           // 391

    // --- CSR build ---
    hipMemsetAsync(cnt, 0, NN * sizeof(u32), stream);
    k_idx<<<EB, 256, 0, stream>>>(ei, out_idx);
    k_deg<<<EB, 256, 0, stream>>>(ei, cnt);
    k_scanA<<<SB, 256, 0, stream>>>(cnt, bsum);
    k_scanB<<<1, 512, 0, stream>>>(bsum, SB);
    k_scanC<<<SB, 256, 0, stream>>>(cnt, bsum, rowptr);
    hipMemsetAsync(cnt, 0, NN * sizeof(u32), stream);
    k_scatter<<<EB, 256, 0, stream>>>(ei, rowptr, cnt, eid);

    // --- node projections + fused attention/aggregation ---
    k_pre<<<(NN * CH) / 256, 256, 0, stream>>>(x, Wl, bl, Wr, br, XL, XR);
    k_fused<<<NN / 4, 256, 0, stream>>>(rowptr, eid, ei, ew, XL, We, att, bgat,
                                        XR, out_alpha);

    // --- GCN + MLP ---
    k_gemm1<<<2048, 256, 0, stream>>>(XR, W2, XL);            // hg -> XL
    k_h2_csr<<<NN / 4, 256, 0, stream>>>(rowptr, eid, ei, out_alpha, XL, XR);
    k_final<<<NN / 4, 256, 0, stream>>>(XR, bgcn, W3, b3, out);
}

// Round 8
// 1011.844 us; speedup vs baseline: 1.3498x; 1.3498x over previous
//
#include <hip/hip_runtime.h>
#include <hip/hip_bf16.h>

#define NN 100000     // nodes
#define NE 1600000    // edges before self loops
#define ET 1700000    // NE + NN
#define CH 128        // hidden channels (H*C, H=1)

typedef unsigned int u32;
typedef unsigned short u16;

__device__ __forceinline__ float lo2f(u32 w) { return __uint_as_float(w << 16); }
__device__ __forceinline__ float hi2f(u32 w) { return __uint_as_float(w & 0xFFFF0000u); }
__device__ __forceinline__ u32 f2bits(float v) {
    __hip_bfloat16 t = __float2bfloat16(v);
    return (u32)*(u16*)&t;
}
__device__ __forceinline__ u32 pack2(float a, float b) {
    return (f2bits(b) << 16) | f2bits(a);
}

// ---------------------------------------------------------------------------
// chunk1: out_idx[e] = f32(src), out_idx[ET+e] = f32(dst)
// ---------------------------------------------------------------------------
__global__ __launch_bounds__(256) void k_idx(
    const int* __restrict__ ei, float* __restrict__ out_idx)
{
    int e = blockIdx.x * 256 + threadIdx.x;
    if (e >= ET) return;
    int s, d;
    if (e < NE) { s = ei[e]; d = ei[NE + e]; }
    else        { s = d = e - NE; }
    out_idx[e]      = (float)s;
    out_idx[ET + e] = (float)d;
}

// ---------------------------------------------------------------------------
// CSR build: cnt[dst]++ -> 2-level exclusive scan -> scatter (eid, esrc, eew)
// ---------------------------------------------------------------------------
__global__ __launch_bounds__(256) void k_deg(
    const int* __restrict__ ei, u32* __restrict__ cnt)
{
    int e = blockIdx.x * 256 + threadIdx.x;
    if (e >= ET) return;
    int d = (e < NE) ? ei[NE + e] : e - NE;
    if ((u32)d >= NN) d = 0;
    atomicAdd(&cnt[d], 1u);
}

__global__ __launch_bounds__(256) void k_scanA(
    const u32* __restrict__ cnt, u32* __restrict__ bsum)
{
    __shared__ u32 s[256];
    int i = blockIdx.x * 256 + threadIdx.x;
    s[threadIdx.x] = (i < NN) ? cnt[i] : 0u;
    __syncthreads();
    for (int off = 128; off; off >>= 1) {
        if (threadIdx.x < off) s[threadIdx.x] += s[threadIdx.x + off];
        __syncthreads();
    }
    if (threadIdx.x == 0) bsum[blockIdx.x] = s[0];
}

__global__ __launch_bounds__(512) void k_scanB(u32* __restrict__ bsum, int nb)
{
    __shared__ u32 s[512];
    int t = threadIdx.x;
    u32 v = (t < nb) ? bsum[t] : 0u;
    s[t] = v; __syncthreads();
    for (int off = 1; off < 512; off <<= 1) {
        u32 a = (t >= off) ? s[t - off] : 0u;
        __syncthreads();
        s[t] += a;
        __syncthreads();
    }
    if (t < nb) bsum[t] = s[t] - v;    // exclusive block offsets
}

__global__ __launch_bounds__(256) void k_scanC(
    const u32* __restrict__ cnt, const u32* __restrict__ bsum,
    u32* __restrict__ rowptr)
{
    __shared__ u32 s[256];
    int i = blockIdx.x * 256 + threadIdx.x;
    u32 v = (i < NN) ? cnt[i] : 0u;
    s[threadIdx.x] = v; __syncthreads();
    for (int off = 1; off < 256; off <<= 1) {
        u32 a = (threadIdx.x >= off) ? s[threadIdx.x - off] : 0u;
        __syncthreads();
        s[threadIdx.x] += a;
        __syncthreads();
    }
    if (i < NN) rowptr[i] = s[threadIdx.x] - v + bsum[blockIdx.x];
    if (i == 0) rowptr[NN] = ET;
}

__global__ __launch_bounds__(256) void k_scatter(
    const int* __restrict__ ei, const float* __restrict__ ew,
    const u32* __restrict__ rowptr, u32* __restrict__ cnt,
    u32* __restrict__ eid, u32* __restrict__ esrc, float2* __restrict__ eew)
{
    int e = blockIdx.x * 256 + threadIdx.x;
    if (e >= ET) return;
    int s, d; float2 w;
    if (e < NE) {
        s = ei[e]; d = ei[NE + e];
        w = make_float2(ew[2 * e], ew[2 * e + 1]);
    } else {
        s = d = e - NE; w = make_float2(0.f, 0.f);
    }
    if ((u32)d >= NN) d = 0;
    if ((u32)s >= NN) s = 0;
    u32 pos = rowptr[d] + atomicAdd(&cnt[d], 1u);
    eid[pos]  = (u32)e;
    esrc[pos] = (u32)s;
    eew[pos]  = w;
}

// ---------------------------------------------------------------------------
// k_pre: xl = x@Wl+bl (bf16-packed), xr = x@Wr+br (f32). Thread = (n, 2 chans)
// ---------------------------------------------------------------------------
__global__ __launch_bounds__(256) void k_pre(
    const float* __restrict__ x,
    const float* __restrict__ Wl, const float* __restrict__ bl,
    const float* __restrict__ Wr, const float* __restrict__ br,
    u32* __restrict__ xlh, float2* __restrict__ xr)
{
    __shared__ float sWl[6][CH], sWr[6][CH], sbl[CH], sbr[CH];
    for (int i = threadIdx.x; i < 6 * CH; i += 256) {
        sWl[i / CH][i % CH] = Wl[i];
        sWr[i / CH][i % CH] = Wr[i];
    }
    for (int i = threadIdx.x; i < CH; i += 256) { sbl[i] = bl[i]; sbr[i] = br[i]; }
    __syncthreads();

    int tid = blockIdx.x * 256 + threadIdx.x;   // grid covers NN*64 exactly
    int n = tid >> 6, c0 = (tid & 63) * 2;
    float xs[6];
#pragma unroll
    for (int k = 0; k < 6; ++k) xs[k] = x[n * 6 + k];
    float l0 = sbl[c0], l1 = sbl[c0 + 1], r0 = sbr[c0], r1 = sbr[c0 + 1];
#pragma unroll
    for (int k = 0; k < 6; ++k) {
        l0 += xs[k] * sWl[k][c0];
        l1 += xs[k] * sWl[k][c0 + 1];
        r0 += xs[k] * sWr[k][c0];
        r1 += xs[k] * sWr[k][c0 + 1];
    }
    xlh[tid] = pack2(l0, l1);
    xr[tid]  = make_float2(r0, r1);
}

// ---------------------------------------------------------------------------
// k_fused (wave/node, single pass):
//   num += ex_e * xl[src_e];  den += ex_e;  out_alpha[e] = ex_e (raw)
//   h[n] = relu(num/den + b_gat)  -> written over xr row (f32)
//   den[n] saved for the k_alpha normalize pass.
// Gathers: one bf16 row (256 B) per edge; eid/esrc/eew are sequential.
// ---------------------------------------------------------------------------
__global__ __launch_bounds__(256) void k_fused(
    const u32* __restrict__ rowptr, const u32* __restrict__ eid,
    const u32* __restrict__ esrc, const float2* __restrict__ eew,
    const u32* __restrict__ xlh,
    const float* __restrict__ We, const float* __restrict__ att,
    const float* __restrict__ bgat,
    float2* __restrict__ xr,         // in: xr ; out: h (in place)
    float* __restrict__ out_alpha, float* __restrict__ den_g)
{
    int n = (blockIdx.x << 2) + (threadIdx.x >> 6);   // grid: NN/4
    int lane = threadIdx.x & 63;
    int c0 = lane * 2;

    float we00 = We[c0], we01 = We[c0 + 1];
    float we10 = We[CH + c0], we11 = We[CH + c0 + 1];
    float at0 = att[c0], at1 = att[c0 + 1];

    float2 xrv = xr[(size_t)n * 64 + lane];
    u32 p0 = rowptr[n], p1 = rowptr[n + 1];

    float den = 0.f, num0 = 0.f, num1 = 0.f;
    for (u32 p = p0; p < p1; ++p) {
        u32 src = esrc[p];
        float2 ea = eew[p];
        u32 xw = xlh[(size_t)src * 64 + lane];
        float xl0 = lo2f(xw), xl1 = hi2f(xw);
        float z0 = xl0 + xrv.x + ea.x * we00 + ea.y * we10;
        float z1 = xl1 + xrv.y + ea.x * we01 + ea.y * we11;
        z0 = z0 > 0.f ? z0 : 0.2f * z0;
        z1 = z1 > 0.f ? z1 : 0.2f * z1;
        float s = z0 * at0 + z1 * at1;
#pragma unroll
        for (int off = 32; off; off >>= 1) s += __shfl_down(s, off, 64);
        s = __shfl(s, 0, 64);
        s = fminf(fmaxf(s, -60.f), 60.f);
        float ex = __expf(s);
        den += ex;
        num0 += ex * xl0;
        num1 += ex * xl1;
        if (lane == 0) out_alpha[eid[p]] = ex;
    }
    float rden = (den > 1e-30f) ? 1.f / den : 0.f;
    if (lane == 0) den_g[n] = den;
    float r0 = num0 * rden + bgat[c0];     r0 = r0 > 0.f ? r0 : 0.f;
    float r1 = num1 * rden + bgat[c0 + 1]; r1 = r1 > 0.f ? r1 : 0.f;
    xr[(size_t)n * 64 + lane] = make_float2(r0, r1);
}

// ---------------------------------------------------------------------------
// k_alpha: out_alpha[e] = ex / den[dst]   (den: 400 KB, L2-hot)
// ---------------------------------------------------------------------------
__global__ __launch_bounds__(256) void k_alpha(
    const int* __restrict__ ei, const float* __restrict__ den_g,
    float* __restrict__ out_alpha)
{
    int e = blockIdx.x * 256 + threadIdx.x;
    if (e >= ET) return;
    int dst = (e < NE) ? ei[NE + e] : e - NE;
    if ((u32)dst >= NN) dst = 0;
    float dn = den_g[dst];
    out_alpha[e] = (dn > 1e-30f) ? out_alpha[e] / dn : 0.f;
}

// ---------------------------------------------------------------------------
// GEMM1: hg = h @ W2 (bf16-packed out). Thread owns column c (W2 col in
// 128 VGPRs); rows via wave-uniform loads; pack pairs via shfl_xor.
// ---------------------------------------------------------------------------
__global__ __launch_bounds__(256, 2) void k_gemm1(
    const float* __restrict__ h, const float* __restrict__ W2,
    u32* __restrict__ hgh)
{
    int c = threadIdx.x & 127;
    int half = threadIdx.x >> 7;
    float w[CH];
#pragma unroll
    for (int k = 0; k < CH; ++k) w[k] = W2[k * CH + c];
    for (int n = blockIdx.x * 2 + half; n < NN; n += gridDim.x * 2) {
        const float* row = h + (size_t)n * CH;
        float acc = 0.f;
#pragma unroll
        for (int k = 0; k < CH; ++k) acc += row[k] * w[k];
        float accO = __shfl_xor(acc, 1, 64);    // partner column (c^1)
        if (!(c & 1))
            hgh[(size_t)n * 64 + (c >> 1)] = pack2(acc, accO);
    }
}

// ---------------------------------------------------------------------------
// k_h2f (wave/node): h2 = sum_e alpha_e * hg[src_e]  (registers only), then
// out[n,:] = relu(h2 + b_gcn) @ W3 + b3.  norm == alpha (deg == 1 identity).
// ---------------------------------------------------------------------------
__global__ __launch_bounds__(256) void k_h2f(
    const u32* __restrict__ rowptr, const u32* __restrict__ eid,
    const u32* __restrict__ esrc, const float* __restrict__ alpha,
    const u32* __restrict__ hgh,
    const float* __restrict__ bgcn, const float* __restrict__ W3,
    const float* __restrict__ b3, float* __restrict__ out)
{
    int n = (blockIdx.x << 2) + (threadIdx.x >> 6);
    int lane = threadIdx.x & 63;
    int c0 = lane * 2;
    u32 p0 = rowptr[n], p1 = rowptr[n + 1];
    float a0 = 0.f, a1 = 0.f;
    for (u32 p = p0; p < p1; ++p) {
        float al = alpha[eid[p]];
        u32 g = hgh[(size_t)esrc[p] * 64 + lane];
        a0 += al * lo2f(g);
        a1 += al * hi2f(g);
    }
    float v0 = a0 + bgcn[c0];     v0 = v0 > 0.f ? v0 : 0.f;
    float v1 = a1 + bgcn[c0 + 1]; v1 = v1 > 0.f ? v1 : 0.f;
    float4 q = *(const float4*)(W3 + 2 * c0);   // W3[c0][0..1], W3[c0+1][0..1]
    float o0 = v0 * q.x + v1 * q.z;
    float o1 = v0 * q.y + v1 * q.w;
#pragma unroll
    for (int off = 32; off; off >>= 1) {
        o0 += __shfl_down(o0, off, 64);
        o1 += __shfl_down(o1, off, 64);
    }
    if (lane == 0) {
        out[n * 2]     = o0 + b3[0];
        out[n * 2 + 1] = o1 + b3[1];
    }
}

// ---------------------------------------------------------------------------
extern "C" void kernel_launch(void* const* d_in, const int* in_sizes, int n_in,
                              void* d_out, int out_size, void* d_ws, size_t ws_size,
                              hipStream_t stream)
{
    const float* x    = (const float*)d_in[0];
    const int*   ei   = (const int*)d_in[1];
    const float* ew   = (const float*)d_in[2];
    const float* Wl   = (const float*)d_in[3];
    const float* bl   = (const float*)d_in[4];
    const float* Wr   = (const float*)d_in[5];
    const float* br   = (const float*)d_in[6];
    const float* We   = (const float*)d_in[7];
    const float* att  = (const float*)d_in[8];
    const float* bgat = (const float*)d_in[9];
    const float* W2   = (const float*)d_in[10];
    const float* bgcn = (const float*)d_in[11];
    const float* W3   = (const float*)d_in[12];
    const float* b3   = (const float*)d_in[13];

    float* out       = (float*)d_out;          // chunk0: out [N,2] f32
    float* out_idx   = out + 200000;           // chunk1: stack([src,dst]) [2,ET]
    float* out_alpha = out + 200000 + 2 * ET;  // chunk2: alpha [ET,1]

    // workspace (~105 MB):
    // XLh u32[NN*64] (xl bf16; later hg bf16) | XR f32[NN*128] (xr -> h)
    // | eid u32[ET] | esrc u32[ET] | eew f32[2*ET] | cnt/den u32[NN]
    // | rowptr u32[NN+1] | bsum u32[512]
    u32*    XLh    = (u32*)d_ws;
    float*  XR     = (float*)(XLh + (size_t)NN * 64);
    u32*    eid    = (u32*)(XR + (size_t)NN * CH);
    u32*    esrc   = eid + ET;
    float2* eew    = (float2*)(esrc + ET);
    u32*    cnt    = (u32*)(eew + ET);
    float*  den    = (float*)cnt;              // aliased after scatter
    u32*    rowptr = cnt + NN;
    u32*    bsum   = rowptr + NN + 1;

    const int EB = (ET + 255) / 256;
    const int SB = (NN + 255) / 256;           // 391

    // --- CSR build ---
    hipMemsetAsync(cnt, 0, NN * sizeof(u32), stream);
    k_idx<<<EB, 256, 0, stream>>>(ei, out_idx);
    k_deg<<<EB, 256, 0, stream>>>(ei, cnt);
    k_scanA<<<SB, 256, 0, stream>>>(cnt, bsum);
    k_scanB<<<1, 512, 0, stream>>>(bsum, SB);
    k_scanC<<<SB, 256, 0, stream>>>(cnt, bsum, rowptr);
    hipMemsetAsync(cnt, 0, NN * sizeof(u32), stream);
    k_scatter<<<EB, 256, 0, stream>>>(ei, ew, rowptr, cnt, eid, esrc, eew);

    // --- projections + fused attention/aggregation ---
    k_pre<<<(NN * 64) / 256, 256, 0, stream>>>(x, Wl, bl, Wr, br, XLh,
                                               (float2*)XR);
    k_fused<<<NN / 4, 256, 0, stream>>>(rowptr, eid, esrc, eew, XLh, We, att,
                                        bgat, (float2*)XR, out_alpha, den);
    k_alpha<<<EB, 256, 0, stream>>>(ei, den, out_alpha);

    // --- GCN + MLP ---
    k_gemm1<<<2048, 256, 0, stream>>>(XR, W2, XLh);          // hg(bf16) -> XLh
    k_h2f<<<NN / 4, 256, 0, stream>>>(rowptr, eid, esrc, out_alpha, XLh,
                                      bgcn, W3, b3, out);
}

// Round 9
// 734.874 us; speedup vs baseline: 1.8585x; 1.3769x over previous
//
#include <hip/hip_runtime.h>
#include <hip/hip_bf16.h>

#define NN 100000     // nodes
#define NE 1600000    // edges before self loops
#define ET 1700000    // NE + NN
#define CH 128        // hidden channels (H*C, H=1)

typedef unsigned int u32;
typedef unsigned short u16;

__device__ __forceinline__ float lo2f(u32 w) { return __uint_as_float(w << 16); }
__device__ __forceinline__ float hi2f(u32 w) { return __uint_as_float(w & 0xFFFF0000u); }
__device__ __forceinline__ u32 f2bits(float v) {
    __hip_bfloat16 t = __float2bfloat16(v);
    return (u32)*(u16*)&t;
}
__device__ __forceinline__ u32 pack2(float a, float b) {
    return (f2bits(b) << 16) | f2bits(a);
}

// ---------------------------------------------------------------------------
// CSR build: cnt[dst]++ -> 2-level exclusive scan -> scatter
// ---------------------------------------------------------------------------
__global__ __launch_bounds__(256) void k_deg(
    const int* __restrict__ ei, u32* __restrict__ cnt)
{
    int e = blockIdx.x * 256 + threadIdx.x;
    if (e >= ET) return;
    int d = (e < NE) ? ei[NE + e] : e - NE;
    if ((u32)d >= NN) d = 0;
    atomicAdd(&cnt[d], 1u);
}

__global__ __launch_bounds__(256) void k_scanA(
    const u32* __restrict__ cnt, u32* __restrict__ bsum)
{
    __shared__ u32 s[256];
    int i = blockIdx.x * 256 + threadIdx.x;
    s[threadIdx.x] = (i < NN) ? cnt[i] : 0u;
    __syncthreads();
    for (int off = 128; off; off >>= 1) {
        if (threadIdx.x < off) s[threadIdx.x] += s[threadIdx.x + off];
        __syncthreads();
    }
    if (threadIdx.x == 0) bsum[blockIdx.x] = s[0];
}

__global__ __launch_bounds__(512) void k_scanB(u32* __restrict__ bsum, int nb)
{
    __shared__ u32 s[512];
    int t = threadIdx.x;
    u32 v = (t < nb) ? bsum[t] : 0u;
    s[t] = v; __syncthreads();
    for (int off = 1; off < 512; off <<= 1) {
        u32 a = (t >= off) ? s[t - off] : 0u;
        __syncthreads();
        s[t] += a;
        __syncthreads();
    }
    if (t < nb) bsum[t] = s[t] - v;    // exclusive block offsets
}

__global__ __launch_bounds__(256) void k_scanC(
    const u32* __restrict__ cnt, const u32* __restrict__ bsum,
    u32* __restrict__ rowptr)
{
    __shared__ u32 s[256];
    int i = blockIdx.x * 256 + threadIdx.x;
    u32 v = (i < NN) ? cnt[i] : 0u;
    s[threadIdx.x] = v; __syncthreads();
    for (int off = 1; off < 256; off <<= 1) {
        u32 a = (threadIdx.x >= off) ? s[threadIdx.x - off] : 0u;
        __syncthreads();
        s[threadIdx.x] += a;
        __syncthreads();
    }
    if (i < NN) rowptr[i] = s[threadIdx.x] - v + bsum[blockIdx.x];
    if (i == 0) rowptr[NN] = ET;
}

// scatter + out_idx emission (merged; ei is read here anyway)
__global__ __launch_bounds__(256) void k_scatter(
    const int* __restrict__ ei, const float* __restrict__ ew,
    const u32* __restrict__ rowptr, u32* __restrict__ cnt,
    u32* __restrict__ eid, u32* __restrict__ esrc, u32* __restrict__ eew,
    float* __restrict__ out_idx)
{
    int e = blockIdx.x * 256 + threadIdx.x;
    if (e >= ET) return;
    int s, d; float w0, w1;
    if (e < NE) {
        s = ei[e]; d = ei[NE + e];
        w0 = ew[2 * e]; w1 = ew[2 * e + 1];
    } else {
        s = d = e - NE; w0 = 0.f; w1 = 0.f;
    }
    out_idx[e]      = (float)s;
    out_idx[ET + e] = (float)d;
    if ((u32)d >= NN) d = 0;
    if ((u32)s >= NN) s = 0;
    u32 pos = rowptr[d] + atomicAdd(&cnt[d], 1u);
    eid[pos]  = (u32)e;
    esrc[pos] = (u32)s;
    eew[pos]  = pack2(w0, w1);
}

// ---------------------------------------------------------------------------
// k_pre: xl = x@Wl+bl (bf16-packed), xr = x@Wr+br (f32). Thread = (n, 2 chans)
// ---------------------------------------------------------------------------
__global__ __launch_bounds__(256) void k_pre(
    const float* __restrict__ x,
    const float* __restrict__ Wl, const float* __restrict__ bl,
    const float* __restrict__ Wr, const float* __restrict__ br,
    u32* __restrict__ xlh, float2* __restrict__ xr)
{
    __shared__ float sWl[6][CH], sWr[6][CH], sbl[CH], sbr[CH];
    for (int i = threadIdx.x; i < 6 * CH; i += 256) {
        sWl[i / CH][i % CH] = Wl[i];
        sWr[i / CH][i % CH] = Wr[i];
    }
    for (int i = threadIdx.x; i < CH; i += 256) { sbl[i] = bl[i]; sbr[i] = br[i]; }
    __syncthreads();

    int tid = blockIdx.x * 256 + threadIdx.x;   // grid covers NN*64 exactly
    int n = tid >> 6, c0 = (tid & 63) * 2;
    float xs[6];
#pragma unroll
    for (int k = 0; k < 6; ++k) xs[k] = x[n * 6 + k];
    float l0 = sbl[c0], l1 = sbl[c0 + 1], r0 = sbr[c0], r1 = sbr[c0 + 1];
#pragma unroll
    for (int k = 0; k < 6; ++k) {
        l0 += xs[k] * sWl[k][c0];
        l1 += xs[k] * sWl[k][c0 + 1];
        r0 += xs[k] * sWr[k][c0];
        r1 += xs[k] * sWr[k][c0 + 1];
    }
    xlh[tid] = pack2(l0, l1);
    xr[tid]  = make_float2(r0, r1);
}

// ---------------------------------------------------------------------------
// k_fused (wave/node; 4 edge-groups of 16 lanes x 8 channels):
//   per edge: z = xl[src] + xr[n] + ea@We; s = att.leaky(z) (16-lane butterfly)
//   ex = exp(s); den += ex; num += ex*xl;  excsr[p] = ex (raw, CSR order)
//   h[n] = relu(num/den + b_gat) -> over xr row; den_g[n] saved.
// ---------------------------------------------------------------------------
__global__ __launch_bounds__(256) void k_fused(
    const u32* __restrict__ rowptr, const u32* __restrict__ esrc,
    const u32* __restrict__ eew, const u32* __restrict__ xlh,
    const float* __restrict__ We, const float* __restrict__ att,
    const float* __restrict__ bgat,
    float* __restrict__ xr,          // in: xr ; out: h (in place)
    float* __restrict__ excsr, float* __restrict__ den_g)
{
    int n = (blockIdx.x << 2) + (threadIdx.x >> 6);   // grid: NN/4
    int lane = threadIdx.x & 63;
    int g = lane >> 4;            // edge-group 0..3
    int gl = lane & 15;           // lane in group
    int c0 = gl * 8;              // 8 channels per lane

    float we0[8], we1[8], at[8];
#pragma unroll
    for (int j = 0; j < 8; ++j) {
        we0[j] = We[c0 + j];
        we1[j] = We[CH + c0 + j];
        at[j]  = att[c0 + j];
    }

    const float4* xr4 = (const float4*)(xr + (size_t)n * CH);
    float4 xa = xr4[gl * 2], xb = xr4[gl * 2 + 1];
    float xrv[8] = {xa.x, xa.y, xa.z, xa.w, xb.x, xb.y, xb.z, xb.w};

    u32 p0 = rowptr[n], p1 = rowptr[n + 1];
    float den = 0.f;
    float num[8] = {0.f, 0.f, 0.f, 0.f, 0.f, 0.f, 0.f, 0.f};

    for (u32 p = p0 + g; p < p1; p += 4) {
        u32 wew = eew[p];                       // broadcast within group
        float ea0 = lo2f(wew), ea1 = hi2f(wew);
        u32 src = esrc[p];
        uint4 w = ((const uint4*)(xlh + (size_t)src * 64))[gl];  // 8 bf16 chans
        float xl[8] = {lo2f(w.x), hi2f(w.x), lo2f(w.y), hi2f(w.y),
                       lo2f(w.z), hi2f(w.z), lo2f(w.w), hi2f(w.w)};
        float s = 0.f;
#pragma unroll
        for (int j = 0; j < 8; ++j) {
            float z = xl[j] + xrv[j] + ea0 * we0[j] + ea1 * we1[j];
            z = z > 0.f ? z : 0.2f * z;         // leaky_relu(0.2)
            s += z * at[j];
        }
        s += __shfl_xor(s, 1, 64);
        s += __shfl_xor(s, 2, 64);
        s += __shfl_xor(s, 4, 64);
        s += __shfl_xor(s, 8, 64);              // all 16 lanes hold s
        s = fminf(fmaxf(s, -60.f), 60.f);
        float ex = __expf(s);
        den += ex;
#pragma unroll
        for (int j = 0; j < 8; ++j) num[j] += ex * xl[j];
        if (gl == 0) excsr[p] = ex;
    }
    // cross-group merge
    den += __shfl_xor(den, 16, 64);
    den += __shfl_xor(den, 32, 64);
#pragma unroll
    for (int j = 0; j < 8; ++j) {
        num[j] += __shfl_xor(num[j], 16, 64);
        num[j] += __shfl_xor(num[j], 32, 64);
    }
    float rden = (den > 1e-30f) ? 1.f / den : 0.f;
    if (lane == 0) den_g[n] = den;
    if (g == 0) {
        float r[8];
#pragma unroll
        for (int j = 0; j < 8; ++j) {
            float v = num[j] * rden + bgat[c0 + j];
            r[j] = v > 0.f ? v : 0.f;
        }
        float4* hrow = (float4*)(xr + (size_t)n * CH);
        hrow[gl * 2]     = make_float4(r[0], r[1], r[2], r[3]);
        hrow[gl * 2 + 1] = make_float4(r[4], r[5], r[6], r[7]);
    }
}

// ---------------------------------------------------------------------------
// GEMM1: hg = h @ W2 (bf16-packed out). Thread owns column c (W2 col in
// 128 VGPRs); rows via wave-uniform loads; pack pairs via shfl_xor.
// ---------------------------------------------------------------------------
__global__ __launch_bounds__(256, 2) void k_gemm1(
    const float* __restrict__ h, const float* __restrict__ W2,
    u32* __restrict__ hgh)
{
    int c = threadIdx.x & 127;
    int half = threadIdx.x >> 7;
    float w[CH];
#pragma unroll
    for (int k = 0; k < CH; ++k) w[k] = W2[k * CH + c];
    for (int n = blockIdx.x * 2 + half; n < NN; n += gridDim.x * 2) {
        const float* row = h + (size_t)n * CH;
        float acc = 0.f;
#pragma unroll
        for (int k = 0; k < CH; ++k) acc += row[k] * w[k];
        float accO = __shfl_xor(acc, 1, 64);    // partner column (c^1)
        if (!(c & 1))
            hgh[(size_t)n * 64 + (c >> 1)] = pack2(acc, accO);
    }
}

// ---------------------------------------------------------------------------
// k_h2f (wave/node; 4 edge-groups of 16):
//   alpha = excsr[p]/den_g[n]; out_alpha[eid[p]] = alpha (scatter);
//   h2 += alpha * hg[src]; out[n,:] = relu(h2+b_gcn)@W3 + b3.
//   (norm == alpha: deg = sum(alpha) == 1 identically)
// ---------------------------------------------------------------------------
__global__ __launch_bounds__(256) void k_h2f(
    const u32* __restrict__ rowptr, const u32* __restrict__ eid,
    const u32* __restrict__ esrc, const float* __restrict__ excsr,
    const float* __restrict__ den_g, const u32* __restrict__ hgh,
    const float* __restrict__ bgcn, const float* __restrict__ W3,
    const float* __restrict__ b3,
    float* __restrict__ out_alpha, float* __restrict__ out)
{
    int n = (blockIdx.x << 2) + (threadIdx.x >> 6);
    int lane = threadIdx.x & 63;
    int g = lane >> 4;
    int gl = lane & 15;
    int c0 = gl * 8;

    float w30[8], w31[8], bg[8];
#pragma unroll
    for (int j = 0; j < 8; ++j) {
        w30[j] = W3[2 * (c0 + j)];
        w31[j] = W3[2 * (c0 + j) + 1];
        bg[j]  = bgcn[c0 + j];
    }

    float dn = den_g[n];
    float rden = (dn > 1e-30f) ? 1.f / dn : 0.f;
    u32 p0 = rowptr[n], p1 = rowptr[n + 1];
    float acc[8] = {0.f, 0.f, 0.f, 0.f, 0.f, 0.f, 0.f, 0.f};

    for (u32 p = p0 + g; p < p1; p += 4) {
        float a = excsr[p] * rden;
        if (gl == 0) out_alpha[eid[p]] = a;
        uint4 w = ((const uint4*)(hgh + (size_t)esrc[p] * 64))[gl];
        acc[0] += a * lo2f(w.x); acc[1] += a * hi2f(w.x);
        acc[2] += a * lo2f(w.y); acc[3] += a * hi2f(w.y);
        acc[4] += a * lo2f(w.z); acc[5] += a * hi2f(w.z);
        acc[6] += a * lo2f(w.w); acc[7] += a * hi2f(w.w);
    }
#pragma unroll
    for (int j = 0; j < 8; ++j) {
        acc[j] += __shfl_xor(acc[j], 16, 64);
        acc[j] += __shfl_xor(acc[j], 32, 64);
    }
    float o0 = 0.f, o1 = 0.f;
#pragma unroll
    for (int j = 0; j < 8; ++j) {
        float v = acc[j] + bg[j];
        v = v > 0.f ? v : 0.f;
        o0 += v * w30[j];
        o1 += v * w31[j];
    }
    o0 += __shfl_xor(o0, 1, 64); o1 += __shfl_xor(o1, 1, 64);
    o0 += __shfl_xor(o0, 2, 64); o1 += __shfl_xor(o1, 2, 64);
    o0 += __shfl_xor(o0, 4, 64); o1 += __shfl_xor(o1, 4, 64);
    o0 += __shfl_xor(o0, 8, 64); o1 += __shfl_xor(o1, 8, 64);
    if (lane == 0) {
        out[n * 2]     = o0 + b3[0];
        out[n * 2 + 1] = o1 + b3[1];
    }
}

// ---------------------------------------------------------------------------
extern "C" void kernel_launch(void* const* d_in, const int* in_sizes, int n_in,
                              void* d_out, int out_size, void* d_ws, size_t ws_size,
                              hipStream_t stream)
{
    const float* x    = (const float*)d_in[0];
    const int*   ei   = (const int*)d_in[1];
    const float* ew   = (const float*)d_in[2];
    const float* Wl   = (const float*)d_in[3];
    const float* bl   = (const float*)d_in[4];
    const float* Wr   = (const float*)d_in[5];
    const float* br   = (const float*)d_in[6];
    const float* We   = (const float*)d_in[7];
    const float* att  = (const float*)d_in[8];
    const float* bgat = (const float*)d_in[9];
    const float* W2   = (const float*)d_in[10];
    const float* bgcn = (const float*)d_in[11];
    const float* W3   = (const float*)d_in[12];
    const float* b3   = (const float*)d_in[13];

    float* out       = (float*)d_out;          // chunk0: out [N,2] f32
    float* out_idx   = out + 200000;           // chunk1: stack([src,dst]) [2,ET]
    float* out_alpha = out + 200000 + 2 * ET;  // chunk2: alpha [ET,1]

    // workspace (~104.5 MB):
    // XLh u32[NN*64] (xl bf16 -> later hg bf16) | XR f32[NN*128] (xr -> h)
    // | eid u32[ET] | esrc u32[ET] | eew u32[ET] (bf16x2) | excsr f32[ET]
    // | cnt u32[NN] (later den_g f32) | rowptr u32[NN+1] | bsum u32[512]
    u32*   XLh    = (u32*)d_ws;
    float* XR     = (float*)(XLh + (size_t)NN * 64);
    u32*   eid    = (u32*)(XR + (size_t)NN * CH);
    u32*   esrc   = eid + ET;
    u32*   eew    = esrc + ET;
    float* excsr  = (float*)(eew + ET);
    u32*   cnt    = (u32*)(excsr + ET);
    float* den    = (float*)cnt;               // aliased after scatter
    u32*   rowptr = cnt + NN;
    u32*   bsum   = rowptr + NN + 1;

    const int EB = (ET + 255) / 256;
    const int SB = (NN + 255) / 256;           // 391

    // --- CSR build (+ out_idx) ---
    hipMemsetAsync(cnt, 0, NN * sizeof(u32), stream);
    k_deg<<<EB, 256, 0, stream>>>(ei, cnt);
    k_scanA<<<SB, 256, 0, stream>>>(cnt, bsum);
    k_scanB<<<1, 512, 0, stream>>>(bsum, SB);
    k_scanC<<<SB, 256, 0, stream>>>(cnt, bsum, rowptr);
    hipMemsetAsync(cnt, 0, NN * sizeof(u32), stream);
    k_scatter<<<EB, 256, 0, stream>>>(ei, ew, rowptr, cnt, eid, esrc, eew,
                                      out_idx);

    // --- projections + fused attention/aggregation ---
    k_pre<<<(NN * 64) / 256, 256, 0, stream>>>(x, Wl, bl, Wr, br, XLh,
                                               (float2*)XR);
    k_fused<<<NN / 4, 256, 0, stream>>>(rowptr, esrc, eew, XLh, We, att, bgat,
                                        XR, excsr, den);

    // --- GCN + MLP ---
    k_gemm1<<<2048, 256, 0, stream>>>(XR, W2, XLh);          // hg(bf16) -> XLh
    k_h2f<<<NN / 4, 256, 0, stream>>>(rowptr, eid, esrc, excsr, den, XLh,
                                      bgcn, W3, b3, out_alpha, out);
}

// Round 10
// 561.991 us; speedup vs baseline: 2.4303x; 1.3076x over previous
//
#include <hip/hip_runtime.h>
#include <hip/hip_bf16.h>

#define NN 100000     // nodes
#define NE 1600000    // edges before self loops
#define ET 1700000    // NE + NN
#define CH 128        // hidden channels (H*C, H=1)

typedef unsigned int u32;
typedef unsigned short u16;

typedef __attribute__((ext_vector_type(8))) short bf16x8;
typedef __attribute__((ext_vector_type(4))) float f32x4;

__device__ __forceinline__ float lo2f(u32 w) { return __uint_as_float(w << 16); }
__device__ __forceinline__ float hi2f(u32 w) { return __uint_as_float(w & 0xFFFF0000u); }
__device__ __forceinline__ u32 f2bits(float v) {
    __hip_bfloat16 t = __float2bfloat16(v);
    return (u32)*(u16*)&t;
}
__device__ __forceinline__ u32 pack2(float a, float b) {
    return (f2bits(b) << 16) | f2bits(a);
}

// ---------------------------------------------------------------------------
// CSR build: cnt[dst]++ -> 2-level exclusive scan -> scatter
// ---------------------------------------------------------------------------
__global__ __launch_bounds__(256) void k_deg(
    const int* __restrict__ ei, u32* __restrict__ cnt)
{
    int e = blockIdx.x * 256 + threadIdx.x;
    if (e >= ET) return;
    int d = (e < NE) ? ei[NE + e] : e - NE;
    if ((u32)d >= NN) d = 0;
    atomicAdd(&cnt[d], 1u);
}

__global__ __launch_bounds__(256) void k_scanA(
    const u32* __restrict__ cnt, u32* __restrict__ bsum)
{
    __shared__ u32 s[256];
    int i = blockIdx.x * 256 + threadIdx.x;
    s[threadIdx.x] = (i < NN) ? cnt[i] : 0u;
    __syncthreads();
    for (int off = 128; off; off >>= 1) {
        if (threadIdx.x < off) s[threadIdx.x] += s[threadIdx.x + off];
        __syncthreads();
    }
    if (threadIdx.x == 0) bsum[blockIdx.x] = s[0];
}

__global__ __launch_bounds__(512) void k_scanB(u32* __restrict__ bsum, int nb)
{
    __shared__ u32 s[512];
    int t = threadIdx.x;
    u32 v = (t < nb) ? bsum[t] : 0u;
    s[t] = v; __syncthreads();
    for (int off = 1; off < 512; off <<= 1) {
        u32 a = (t >= off) ? s[t - off] : 0u;
        __syncthreads();
        s[t] += a;
        __syncthreads();
    }
    if (t < nb) bsum[t] = s[t] - v;    // exclusive block offsets
}

__global__ __launch_bounds__(256) void k_scanC(
    const u32* __restrict__ cnt, const u32* __restrict__ bsum,
    u32* __restrict__ rowptr)
{
    __shared__ u32 s[256];
    int i = blockIdx.x * 256 + threadIdx.x;
    u32 v = (i < NN) ? cnt[i] : 0u;
    s[threadIdx.x] = v; __syncthreads();
    for (int off = 1; off < 256; off <<= 1) {
        u32 a = (threadIdx.x >= off) ? s[threadIdx.x - off] : 0u;
        __syncthreads();
        s[threadIdx.x] += a;
        __syncthreads();
    }
    if (i < NN) rowptr[i] = s[threadIdx.x] - v + bsum[blockIdx.x];
    if (i == 0) rowptr[NN] = ET;
}

// scatter + out_idx emission (merged; ei is read here anyway)
__global__ __launch_bounds__(256) void k_scatter(
    const int* __restrict__ ei, const float* __restrict__ ew,
    const u32* __restrict__ rowptr, u32* __restrict__ cnt,
    u32* __restrict__ eid, u32* __restrict__ esrc, u32* __restrict__ eew,
    float* __restrict__ out_idx)
{
    int e = blockIdx.x * 256 + threadIdx.x;
    if (e >= ET) return;
    int s, d; float w0, w1;
    if (e < NE) {
        s = ei[e]; d = ei[NE + e];
        w0 = ew[2 * e]; w1 = ew[2 * e + 1];
    } else {
        s = d = e - NE; w0 = 0.f; w1 = 0.f;
    }
    out_idx[e]      = (float)s;
    out_idx[ET + e] = (float)d;
    if ((u32)d >= NN) d = 0;
    if ((u32)s >= NN) s = 0;
    u32 pos = rowptr[d] + atomicAdd(&cnt[d], 1u);
    eid[pos]  = (u32)e;
    esrc[pos] = (u32)s;
    eew[pos]  = pack2(w0, w1);
}

// ---------------------------------------------------------------------------
// k_pre: xl = x@Wl+bl (bf16-packed), xr = x@Wr+br (f32). Thread = (n, 2 chans)
// ---------------------------------------------------------------------------
__global__ __launch_bounds__(256) void k_pre(
    const float* __restrict__ x,
    const float* __restrict__ Wl, const float* __restrict__ bl,
    const float* __restrict__ Wr, const float* __restrict__ br,
    u32* __restrict__ xlh, float2* __restrict__ xr)
{
    __shared__ float sWl[6][CH], sWr[6][CH], sbl[CH], sbr[CH];
    for (int i = threadIdx.x; i < 6 * CH; i += 256) {
        sWl[i / CH][i % CH] = Wl[i];
        sWr[i / CH][i % CH] = Wr[i];
    }
    for (int i = threadIdx.x; i < CH; i += 256) { sbl[i] = bl[i]; sbr[i] = br[i]; }
    __syncthreads();

    int tid = blockIdx.x * 256 + threadIdx.x;   // grid covers NN*64 exactly
    int n = tid >> 6, c0 = (tid & 63) * 2;
    float xs[6];
#pragma unroll
    for (int k = 0; k < 6; ++k) xs[k] = x[n * 6 + k];
    float l0 = sbl[c0], l1 = sbl[c0 + 1], r0 = sbr[c0], r1 = sbr[c0 + 1];
#pragma unroll
    for (int k = 0; k < 6; ++k) {
        l0 += xs[k] * sWl[k][c0];
        l1 += xs[k] * sWl[k][c0 + 1];
        r0 += xs[k] * sWr[k][c0];
        r1 += xs[k] * sWr[k][c0 + 1];
    }
    xlh[tid] = pack2(l0, l1);
    xr[tid]  = make_float2(r0, r1);
}

// ---------------------------------------------------------------------------
// k_fused (wave/node; 4 edge-groups of 16 lanes x 8 channels):
//   per edge: z = xl[src] + xr[n] + ea@We; s = att.leaky(z) (16-lane butterfly)
//   ex = exp(s); den += ex; num += ex*xl;  excsr[p] = ex (raw, CSR order)
//   h[n] = relu(num/den + b_gat) -> stored as BF16 row (256 B) in the first
//   half of node n's 512 B xr slot (only node n's wave touches slot n; all
//   xr reads precede the write within the same wave -> race-free).
// ---------------------------------------------------------------------------
__global__ __launch_bounds__(256) void k_fused(
    const u32* __restrict__ rowptr, const u32* __restrict__ esrc,
    const u32* __restrict__ eew, const u32* __restrict__ xlh,
    const float* __restrict__ We, const float* __restrict__ att,
    const float* __restrict__ bgat,
    float* __restrict__ xr,          // in: xr f32 ; out: h bf16 (interleaved)
    float* __restrict__ excsr, float* __restrict__ den_g)
{
    int n = (blockIdx.x << 2) + (threadIdx.x >> 6);   // grid: NN/4
    int lane = threadIdx.x & 63;
    int g = lane >> 4;            // edge-group 0..3
    int gl = lane & 15;           // lane in group
    int c0 = gl * 8;              // 8 channels per lane

    float we0[8], we1[8], at[8];
#pragma unroll
    for (int j = 0; j < 8; ++j) {
        we0[j] = We[c0 + j];
        we1[j] = We[CH + c0 + j];
        at[j]  = att[c0 + j];
    }

    const float4* xr4 = (const float4*)(xr + (size_t)n * CH);
    float4 xa = xr4[gl * 2], xb = xr4[gl * 2 + 1];
    float xrv[8] = {xa.x, xa.y, xa.z, xa.w, xb.x, xb.y, xb.z, xb.w};

    u32 p0 = rowptr[n], p1 = rowptr[n + 1];
    float den = 0.f;
    float num[8] = {0.f, 0.f, 0.f, 0.f, 0.f, 0.f, 0.f, 0.f};

    for (u32 p = p0 + g; p < p1; p += 4) {
        u32 wew = eew[p];                       // broadcast within group
        float ea0 = lo2f(wew), ea1 = hi2f(wew);
        u32 src = esrc[p];
        uint4 w = ((const uint4*)(xlh + (size_t)src * 64))[gl];  // 8 bf16 chans
        float xl[8] = {lo2f(w.x), hi2f(w.x), lo2f(w.y), hi2f(w.y),
                       lo2f(w.z), hi2f(w.z), lo2f(w.w), hi2f(w.w)};
        float s = 0.f;
#pragma unroll
        for (int j = 0; j < 8; ++j) {
            float z = xl[j] + xrv[j] + ea0 * we0[j] + ea1 * we1[j];
            z = z > 0.f ? z : 0.2f * z;         // leaky_relu(0.2)
            s += z * at[j];
        }
        s += __shfl_xor(s, 1, 64);
        s += __shfl_xor(s, 2, 64);
        s += __shfl_xor(s, 4, 64);
        s += __shfl_xor(s, 8, 64);              // all 16 lanes hold s
        s = fminf(fmaxf(s, -60.f), 60.f);
        float ex = __expf(s);
        den += ex;
#pragma unroll
        for (int j = 0; j < 8; ++j) num[j] += ex * xl[j];
        if (gl == 0) excsr[p] = ex;
    }
    // cross-group merge
    den += __shfl_xor(den, 16, 64);
    den += __shfl_xor(den, 32, 64);
#pragma unroll
    for (int j = 0; j < 8; ++j) {
        num[j] += __shfl_xor(num[j], 16, 64);
        num[j] += __shfl_xor(num[j], 32, 64);
    }
    float rden = (den > 1e-30f) ? 1.f / den : 0.f;
    if (lane == 0) den_g[n] = den;
    if (g == 0) {
        float r[8];
#pragma unroll
        for (int j = 0; j < 8; ++j) {
            float v = num[j] * rden + bgat[c0 + j];
            r[j] = v > 0.f ? v : 0.f;
        }
        // bf16 h-row into first 256 B of this node's xr slot
        uint4* hrow = (uint4*)((u16*)xr + (size_t)n * 256);
        hrow[gl] = make_uint4(pack2(r[0], r[1]), pack2(r[2], r[3]),
                              pack2(r[4], r[5]), pack2(r[6], r[7]));
    }
}

// ---------------------------------------------------------------------------
// GEMM1 (MFMA): hg = h @ W2, bf16 in/out.
//   A = h bf16 rows (stride 256 u16, interleaved in XR slots)
//   B = W2 f32 -> bf16 fragments in 128 VGPRs (loaded once per block)
//   Wave computes a 16-row x 128-col strip; block (4 waves) = 64 rows/chunk.
//   Fragment layouts (HW-verified m89/m91/m120):
//     A[m=lane&15][k=quad*8+j], B[k=quad*8+j][n=lane&15],
//     D col=lane&15, row=quad*4+reg.
// ---------------------------------------------------------------------------
__global__ __launch_bounds__(256) void k_gemm1(
    const u16* __restrict__ hb, const float* __restrict__ W2,
    u16* __restrict__ hgh)
{
    int lane = threadIdx.x & 63;
    int wv = threadIdx.x >> 6;
    int quad = lane >> 4;
    int l15 = lane & 15;

    // B fragments [kc][n0], once per block (W2 is L2-hot)
    bf16x8 bfrag[4][8];
#pragma unroll
    for (int kc = 0; kc < 4; ++kc) {
#pragma unroll
        for (int n0 = 0; n0 < 8; ++n0) {
            int kbase = kc * 32 + quad * 8;
            int col = n0 * 16 + l15;
            union { bf16x8 v; u32 u[4]; } t;
#pragma unroll
            for (int jj = 0; jj < 4; ++jj) {
                float w0 = W2[(kbase + 2 * jj) * CH + col];
                float w1 = W2[(kbase + 2 * jj + 1) * CH + col];
                t.u[jj] = pack2(w0, w1);
            }
            bfrag[kc][n0] = t.v;
        }
    }

    const int nchunk = (NN + 63) / 64;       // 1563
    for (int ch = blockIdx.x; ch < nchunk; ch += gridDim.x) {
        int m0 = ch * 64 + wv * 16;
        int arow = m0 + l15;
        if (arow >= NN) arow = NN - 1;       // clamp (stores guarded)
        const uint4* ap = (const uint4*)(hb + (size_t)arow * 256);

        bf16x8 afrag[4];
#pragma unroll
        for (int kc = 0; kc < 4; ++kc) {
            union { uint4 q; bf16x8 v; } t;
            t.q = ap[kc * 4 + quad];
            afrag[kc] = t.v;
        }

        f32x4 acc[8];
#pragma unroll
        for (int n0 = 0; n0 < 8; ++n0) acc[n0] = (f32x4){0.f, 0.f, 0.f, 0.f};
#pragma unroll
        for (int n0 = 0; n0 < 8; ++n0)
#pragma unroll
            for (int kc = 0; kc < 4; ++kc)
                acc[n0] = __builtin_amdgcn_mfma_f32_16x16x32_bf16(
                    afrag[kc], bfrag[kc][n0], acc[n0], 0, 0, 0);

#pragma unroll
        for (int n0 = 0; n0 < 8; ++n0) {
#pragma unroll
            for (int r = 0; r < 4; ++r) {
                int row = m0 + quad * 4 + r;
                if (row < NN)
                    hgh[(size_t)row * CH + n0 * 16 + l15] =
                        (u16)f2bits(acc[n0][r]);
            }
        }
    }
}

// ---------------------------------------------------------------------------
// k_h2f (wave/node; 4 edge-groups of 16):
//   alpha = excsr[p]/den_g[n]; out_alpha[eid[p]] = alpha (scatter);
//   h2 += alpha * hg[src]; out[n,:] = relu(h2+b_gcn)@W3 + b3.
//   (norm == alpha: deg = sum(alpha) == 1 identically)
// ---------------------------------------------------------------------------
__global__ __launch_bounds__(256) void k_h2f(
    const u32* __restrict__ rowptr, const u32* __restrict__ eid,
    const u32* __restrict__ esrc, const float* __restrict__ excsr,
    const float* __restrict__ den_g, const u32* __restrict__ hgh,
    const float* __restrict__ bgcn, const float* __restrict__ W3,
    const float* __restrict__ b3,
    float* __restrict__ out_alpha, float* __restrict__ out)
{
    int n = (blockIdx.x << 2) + (threadIdx.x >> 6);
    int lane = threadIdx.x & 63;
    int g = lane >> 4;
    int gl = lane & 15;
    int c0 = gl * 8;

    float w30[8], w31[8], bg[8];
#pragma unroll
    for (int j = 0; j < 8; ++j) {
        w30[j] = W3[2 * (c0 + j)];
        w31[j] = W3[2 * (c0 + j) + 1];
        bg[j]  = bgcn[c0 + j];
    }

    float dn = den_g[n];
    float rden = (dn > 1e-30f) ? 1.f / dn : 0.f;
    u32 p0 = rowptr[n], p1 = rowptr[n + 1];
    float acc[8] = {0.f, 0.f, 0.f, 0.f, 0.f, 0.f, 0.f, 0.f};

    for (u32 p = p0 + g; p < p1; p += 4) {
        float a = excsr[p] * rden;
        if (gl == 0) out_alpha[eid[p]] = a;
        uint4 w = ((const uint4*)(hgh + (size_t)esrc[p] * 64))[gl];
        acc[0] += a * lo2f(w.x); acc[1] += a * hi2f(w.x);
        acc[2] += a * lo2f(w.y); acc[3] += a * hi2f(w.y);
        acc[4] += a * lo2f(w.z); acc[5] += a * hi2f(w.z);
        acc[6] += a * lo2f(w.w); acc[7] += a * hi2f(w.w);
    }
#pragma unroll
    for (int j = 0; j < 8; ++j) {
        acc[j] += __shfl_xor(acc[j], 16, 64);
        acc[j] += __shfl_xor(acc[j], 32, 64);
    }
    float o0 = 0.f, o1 = 0.f;
#pragma unroll
    for (int j = 0; j < 8; ++j) {
        float v = acc[j] + bg[j];
        v = v > 0.f ? v : 0.f;
        o0 += v * w30[j];
        o1 += v * w31[j];
    }
    o0 += __shfl_xor(o0, 1, 64); o1 += __shfl_xor(o1, 1, 64);
    o0 += __shfl_xor(o0, 2, 64); o1 += __shfl_xor(o1, 2, 64);
    o0 += __shfl_xor(o0, 4, 64); o1 += __shfl_xor(o1, 4, 64);
    o0 += __shfl_xor(o0, 8, 64); o1 += __shfl_xor(o1, 8, 64);
    if (lane == 0) {
        out[n * 2]     = o0 + b3[0];
        out[n * 2 + 1] = o1 + b3[1];
    }
}

// ---------------------------------------------------------------------------
extern "C" void kernel_launch(void* const* d_in, const int* in_sizes, int n_in,
                              void* d_out, int out_size, void* d_ws, size_t ws_size,
                              hipStream_t stream)
{
    const float* x    = (const float*)d_in[0];
    const int*   ei   = (const int*)d_in[1];
    const float* ew   = (const float*)d_in[2];
    const float* Wl   = (const float*)d_in[3];
    const float* bl   = (const float*)d_in[4];
    const float* Wr   = (const float*)d_in[5];
    const float* br   = (const float*)d_in[6];
    const float* We   = (const float*)d_in[7];
    const float* att  = (const float*)d_in[8];
    const float* bgat = (const float*)d_in[9];
    const float* W2   = (const float*)d_in[10];
    const float* bgcn = (const float*)d_in[11];
    const float* W3   = (const float*)d_in[12];
    const float* b3   = (const float*)d_in[13];

    float* out       = (float*)d_out;          // chunk0: out [N,2] f32
    float* out_idx   = out + 200000;           // chunk1: stack([src,dst]) [2,ET]
    float* out_alpha = out + 200000 + 2 * ET;  // chunk2: alpha [ET,1]

    // workspace (~104.5 MB):
    // XLh u32[NN*64] (xl bf16 -> later hg bf16) | XR f32[NN*128] (xr -> h bf16)
    // | eid u32[ET] | esrc u32[ET] | eew u32[ET] (bf16x2) | excsr f32[ET]
    // | cnt u32[NN] (later den_g f32) | rowptr u32[NN+1] | bsum u32[512]
    u32*   XLh    = (u32*)d_ws;
    float* XR     = (float*)(XLh + (size_t)NN * 64);
    u32*   eid    = (u32*)(XR + (size_t)NN * CH);
    u32*   esrc   = eid + ET;
    u32*   eew    = esrc + ET;
    float* excsr  = (float*)(eew + ET);
    u32*   cnt    = (u32*)(excsr + ET);
    float* den    = (float*)cnt;               // aliased after scatter
    u32*   rowptr = cnt + NN;
    u32*   bsum   = rowptr + NN + 1;

    const int EB = (ET + 255) / 256;
    const int SB = (NN + 255) / 256;           // 391

    // --- CSR build (+ out_idx) ---
    hipMemsetAsync(cnt, 0, NN * sizeof(u32), stream);
    k_deg<<<EB, 256, 0, stream>>>(ei, cnt);
    k_scanA<<<SB, 256, 0, stream>>>(cnt, bsum);
    k_scanB<<<1, 512, 0, stream>>>(bsum, SB);
    k_scanC<<<SB, 256, 0, stream>>>(cnt, bsum, rowptr);
    hipMemsetAsync(cnt, 0, NN * sizeof(u32), stream);
    k_scatter<<<EB, 256, 0, stream>>>(ei, ew, rowptr, cnt, eid, esrc, eew,
                                      out_idx);

    // --- projections + fused attention/aggregation ---
    k_pre<<<(NN * 64) / 256, 256, 0, stream>>>(x, Wl, bl, Wr, br, XLh,
                                               (float2*)XR);
    k_fused<<<NN / 4, 256, 0, stream>>>(rowptr, esrc, eew, XLh, We, att, bgat,
                                        XR, excsr, den);

    // --- GCN (MFMA) + MLP ---
    k_gemm1<<<512, 256, 0, stream>>>((const u16*)XR, W2, (u16*)XLh);
    k_h2f<<<NN / 4, 256, 0, stream>>>(rowptr, eid, esrc, excsr, den, XLh,
                                      bgcn, W3, b3, out_alpha, out);
}

// Round 12
// 548.177 us; speedup vs baseline: 2.4915x; 1.0252x over previous
//
#include <hip/hip_runtime.h>
#include <hip/hip_bf16.h>

#define NN 100000     // nodes
#define NE 1600000    // edges before self loops
#define ET 1700000    // NE + NN
#define CH 128        // hidden channels (H*C, H=1)

typedef unsigned int u32;
typedef unsigned short u16;

typedef __attribute__((ext_vector_type(8))) short bf16x8;
typedef __attribute__((ext_vector_type(4))) float f32x4;
typedef __attribute__((ext_vector_type(2))) float f32x2;

__device__ __forceinline__ float lo2f(u32 w) { return __uint_as_float(w << 16); }
__device__ __forceinline__ float hi2f(u32 w) { return __uint_as_float(w & 0xFFFF0000u); }
__device__ __forceinline__ u32 f2bits(float v) {
    __hip_bfloat16 t = __float2bfloat16(v);
    return (u32)*(u16*)&t;
}
__device__ __forceinline__ u32 pack2(float a, float b) {
    return (f2bits(b) << 16) | f2bits(a);
}
// fp8 e4m3 HW converts — word-select must be a compile-time constant
template<bool HI>
__device__ __forceinline__ int pk_fp8(float a, float b, int old) {
    return __builtin_amdgcn_cvt_pk_fp8_f32(a, b, old, HI);
}
template<bool HI>
__device__ __forceinline__ f32x2 unpk_fp8(u32 w) {
    return __builtin_amdgcn_cvt_pk_f32_fp8((int)w, HI);
}

// ---------------------------------------------------------------------------
// CSR build: cnt[dst]++ -> 2-level exclusive scan -> scatter
// ---------------------------------------------------------------------------
__global__ __launch_bounds__(256) void k_deg(
    const int* __restrict__ ei, u32* __restrict__ cnt)
{
    int e = blockIdx.x * 256 + threadIdx.x;
    if (e >= ET) return;
    int d = (e < NE) ? ei[NE + e] : e - NE;
    if ((u32)d >= NN) d = 0;
    atomicAdd(&cnt[d], 1u);
}

__global__ __launch_bounds__(256) void k_scanA(
    const u32* __restrict__ cnt, u32* __restrict__ bsum)
{
    __shared__ u32 s[256];
    int i = blockIdx.x * 256 + threadIdx.x;
    s[threadIdx.x] = (i < NN) ? cnt[i] : 0u;
    __syncthreads();
    for (int off = 128; off; off >>= 1) {
        if (threadIdx.x < off) s[threadIdx.x] += s[threadIdx.x + off];
        __syncthreads();
    }
    if (threadIdx.x == 0) bsum[blockIdx.x] = s[0];
}

__global__ __launch_bounds__(512) void k_scanB(u32* __restrict__ bsum, int nb)
{
    __shared__ u32 s[512];
    int t = threadIdx.x;
    u32 v = (t < nb) ? bsum[t] : 0u;
    s[t] = v; __syncthreads();
    for (int off = 1; off < 512; off <<= 1) {
        u32 a = (t >= off) ? s[t - off] : 0u;
        __syncthreads();
        s[t] += a;
        __syncthreads();
    }
    if (t < nb) bsum[t] = s[t] - v;    // exclusive block offsets
}

__global__ __launch_bounds__(256) void k_scanC(
    const u32* __restrict__ cnt, const u32* __restrict__ bsum,
    u32* __restrict__ rowptr)
{
    __shared__ u32 s[256];
    int i = blockIdx.x * 256 + threadIdx.x;
    u32 v = (i < NN) ? cnt[i] : 0u;
    s[threadIdx.x] = v; __syncthreads();
    for (int off = 1; off < 256; off <<= 1) {
        u32 a = (threadIdx.x >= off) ? s[threadIdx.x - off] : 0u;
        __syncthreads();
        s[threadIdx.x] += a;
        __syncthreads();
    }
    if (i < NN) rowptr[i] = s[threadIdx.x] - v + bsum[blockIdx.x];
    if (i == 0) rowptr[NN] = ET;
}

// scatter one 16B edge record {src, ew(bf16x2), eid, (ex later)} + out_idx
__global__ __launch_bounds__(256) void k_scatter(
    const int* __restrict__ ei, const float* __restrict__ ew,
    const u32* __restrict__ rowptr, u32* __restrict__ cnt,
    uint4* __restrict__ erec, float* __restrict__ out_idx)
{
    int e = blockIdx.x * 256 + threadIdx.x;
    if (e >= ET) return;
    int s, d; float w0, w1;
    if (e < NE) {
        s = ei[e]; d = ei[NE + e];
        w0 = ew[2 * e]; w1 = ew[2 * e + 1];
    } else {
        s = d = e - NE; w0 = 0.f; w1 = 0.f;
    }
    out_idx[e]      = (float)s;
    out_idx[ET + e] = (float)d;
    if ((u32)d >= NN) d = 0;
    if ((u32)s >= NN) s = 0;
    u32 pos = rowptr[d] + atomicAdd(&cnt[d], 1u);
    erec[pos] = make_uint4((u32)s, pack2(w0, w1), (u32)e, 0u);
}

// ---------------------------------------------------------------------------
// k_pre: xl = x@Wl+bl -> fp8 (128 B/row); xr = x@Wr+br -> bf16 (256 B/row)
// Thread = (n, 4 channels).
// ---------------------------------------------------------------------------
__global__ __launch_bounds__(256) void k_pre(
    const float* __restrict__ x,
    const float* __restrict__ Wl, const float* __restrict__ bl,
    const float* __restrict__ Wr, const float* __restrict__ br,
    u32* __restrict__ xl8, uint2* __restrict__ xrh)
{
    __shared__ float sWl[6][CH], sWr[6][CH], sbl[CH], sbr[CH];
    for (int i = threadIdx.x; i < 6 * CH; i += 256) {
        sWl[i / CH][i % CH] = Wl[i];
        sWr[i / CH][i % CH] = Wr[i];
    }
    for (int i = threadIdx.x; i < CH; i += 256) { sbl[i] = bl[i]; sbr[i] = br[i]; }
    __syncthreads();

    int tid = blockIdx.x * 256 + threadIdx.x;   // grid covers NN*32 exactly
    int n = tid >> 5, q = tid & 31, c0 = q * 4;
    float xs[6];
#pragma unroll
    for (int k = 0; k < 6; ++k) xs[k] = x[n * 6 + k];
    float l[4], r[4];
#pragma unroll
    for (int j = 0; j < 4; ++j) { l[j] = sbl[c0 + j]; r[j] = sbr[c0 + j]; }
#pragma unroll
    for (int k = 0; k < 6; ++k)
#pragma unroll
        for (int j = 0; j < 4; ++j) {
            l[j] += xs[k] * sWl[k][c0 + j];
            r[j] += xs[k] * sWr[k][c0 + j];
        }
    int v = pk_fp8<false>(l[0], l[1], 0);
    v = pk_fp8<true>(l[2], l[3], v);
    xl8[tid] = (u32)v;                               // bytes = channels c0..c0+3
    xrh[tid] = make_uint2(pack2(r[0], r[1]), pack2(r[2], r[3]));
}

// ---------------------------------------------------------------------------
// k_fused (wave/node; 4 edge-groups of 16 lanes x 8 channels):
//   per edge: z = xl[src] + xr[n] + ea@We; s = att.leaky(z) (16-lane butterfly)
//   ex = exp(s) -> erec[p].w;  den += ex; num += ex*xl
//   h[n] = relu(num/den + b_gat) -> bf16 row written OVER xr slot n (race-free:
//   only node n's wave touches slot n, reads precede the write).
// ---------------------------------------------------------------------------
__global__ __launch_bounds__(256) void k_fused(
    const u32* __restrict__ rowptr, uint4* erec,
    const u32* __restrict__ xl8,
    const float* __restrict__ We, const float* __restrict__ att,
    const float* __restrict__ bgat,
    uint4* xr,                        // in: xr bf16 ; out: h bf16 (in place)
    float* __restrict__ den_g)
{
    int n = (blockIdx.x << 2) + (threadIdx.x >> 6);   // grid: NN/4
    int lane = threadIdx.x & 63;
    int g = lane >> 4;            // edge-group 0..3
    int gl = lane & 15;           // lane in group
    int c0 = gl * 8;              // 8 channels per lane

    float we0[8], we1[8], at[8];
#pragma unroll
    for (int j = 0; j < 8; ++j) {
        we0[j] = We[c0 + j];
        we1[j] = We[CH + c0 + j];
        at[j]  = att[c0 + j];
    }

    uint4 xw = xr[(size_t)n * 16 + gl];   // 8 bf16 channels
    float xrv[8] = {lo2f(xw.x), hi2f(xw.x), lo2f(xw.y), hi2f(xw.y),
                    lo2f(xw.z), hi2f(xw.z), lo2f(xw.w), hi2f(xw.w)};

    u32 p0 = rowptr[n], p1 = rowptr[n + 1];
    float den = 0.f;
    float num[8] = {0.f, 0.f, 0.f, 0.f, 0.f, 0.f, 0.f, 0.f};

    for (u32 p = p0 + g; p < p1; p += 4) {
        uint4 er = erec[p];                      // broadcast within group
        float ea0 = lo2f(er.y), ea1 = hi2f(er.y);
        uint2 w = ((const uint2*)xl8)[(size_t)er.x * 16 + gl];  // 8 fp8 chans
        f32x2 d0 = unpk_fp8<false>(w.x), d1 = unpk_fp8<true>(w.x);
        f32x2 d2 = unpk_fp8<false>(w.y), d3 = unpk_fp8<true>(w.y);
        float xl[8] = {d0.x, d0.y, d1.x, d1.y, d2.x, d2.y, d3.x, d3.y};
        float s = 0.f;
#pragma unroll
        for (int j = 0; j < 8; ++j) {
            float z = xl[j] + xrv[j] + ea0 * we0[j] + ea1 * we1[j];
            z = z > 0.f ? z : 0.2f * z;         // leaky_relu(0.2)
            s += z * at[j];
        }
        s += __shfl_xor(s, 1, 64);
        s += __shfl_xor(s, 2, 64);
        s += __shfl_xor(s, 4, 64);
        s += __shfl_xor(s, 8, 64);              // all 16 lanes hold s
        s = fminf(fmaxf(s, -60.f), 60.f);
        float ex = __expf(s);
        den += ex;
#pragma unroll
        for (int j = 0; j < 8; ++j) num[j] += ex * xl[j];
        if (gl == 0) erec[p].w = __float_as_uint(ex);
    }
    // cross-group merge
    den += __shfl_xor(den, 16, 64);
    den += __shfl_xor(den, 32, 64);
#pragma unroll
    for (int j = 0; j < 8; ++j) {
        num[j] += __shfl_xor(num[j], 16, 64);
        num[j] += __shfl_xor(num[j], 32, 64);
    }
    float rden = (den > 1e-30f) ? 1.f / den : 0.f;
    if (lane == 0) den_g[n] = den;
    if (g == 0) {
        float r[8];
#pragma unroll
        for (int j = 0; j < 8; ++j) {
            float v = num[j] * rden + bgat[c0 + j];
            r[j] = v > 0.f ? v : 0.f;
        }
        xr[(size_t)n * 16 + gl] = make_uint4(pack2(r[0], r[1]), pack2(r[2], r[3]),
                                             pack2(r[4], r[5]), pack2(r[6], r[7]));
    }
}

// ---------------------------------------------------------------------------
// GEMM1 (MFMA): hg = h @ W2; h bf16 rows (256 B), hg -> fp8 rows (128 B).
//   hg byte layout: row n, lane-l15 slot holds channels {16j+l15, j=0..7}
//   (k_h2f uses the same map; the final W3 reduction is lane-order agnostic).
//   Fragment layouts (HW-verified m89/m91/m120):
//     A[m=lane&15][k=quad*8+j], B[k=quad*8+j][n=lane&15], D col=lane&15,
//     row=quad*4+reg.
// ---------------------------------------------------------------------------
__global__ __launch_bounds__(256) void k_gemm1(
    const u32* __restrict__ hb, const float* __restrict__ W2,
    uint2* __restrict__ hg8)
{
    int lane = threadIdx.x & 63;
    int wv = threadIdx.x >> 6;
    int quad = lane >> 4;
    int l15 = lane & 15;

    // B fragments [kc][n0], once per block (W2 is L2-hot)
    bf16x8 bfrag[4][8];
#pragma unroll
    for (int kc = 0; kc < 4; ++kc) {
#pragma unroll
        for (int n0 = 0; n0 < 8; ++n0) {
            int kbase = kc * 32 + quad * 8;
            int col = n0 * 16 + l15;
            union { bf16x8 v; u32 u[4]; } t;
#pragma unroll
            for (int jj = 0; jj < 4; ++jj) {
                float w0 = W2[(kbase + 2 * jj) * CH + col];
                float w1 = W2[(kbase + 2 * jj + 1) * CH + col];
                t.u[jj] = pack2(w0, w1);
            }
            bfrag[kc][n0] = t.v;
        }
    }

    const int nchunk = (NN + 63) / 64;       // 1563
    for (int ch = blockIdx.x; ch < nchunk; ch += gridDim.x) {
        int m0 = ch * 64 + wv * 16;
        int arow = m0 + l15;
        if (arow >= NN) arow = NN - 1;       // clamp (stores guarded)
        const uint4* ap = (const uint4*)(hb + (size_t)arow * 64);

        bf16x8 afrag[4];
#pragma unroll
        for (int kc = 0; kc < 4; ++kc) {
            union { uint4 q; bf16x8 v; } t;
            t.q = ap[kc * 4 + quad];
            afrag[kc] = t.v;
        }

        f32x4 acc[8];
#pragma unroll
        for (int n0 = 0; n0 < 8; ++n0) acc[n0] = (f32x4){0.f, 0.f, 0.f, 0.f};
#pragma unroll
        for (int n0 = 0; n0 < 8; ++n0)
#pragma unroll
            for (int kc = 0; kc < 4; ++kc)
                acc[n0] = __builtin_amdgcn_mfma_f32_16x16x32_bf16(
                    afrag[kc], bfrag[kc][n0], acc[n0], 0, 0, 0);

#pragma unroll
        for (int r = 0; r < 4; ++r) {
            int row = m0 + quad * 4 + r;
            if (row < NN) {
                int a = pk_fp8<false>(acc[0][r], acc[1][r], 0);
                a = pk_fp8<true>(acc[2][r], acc[3][r], a);
                int b = pk_fp8<false>(acc[4][r], acc[5][r], 0);
                b = pk_fp8<true>(acc[6][r], acc[7][r], b);
                hg8[(size_t)row * 16 + l15] = make_uint2((u32)a, (u32)b);
            }
        }
    }
}

// ---------------------------------------------------------------------------
// k_h2f (wave/node; 4 edge-groups of 16):
//   one 16B erec load/edge: {src, -, eid, ex}; alpha = ex/den_g[n];
//   out_alpha[eid] = alpha; h2 += alpha * hg8[src] (fp8 decode, chans 16j+gl);
//   out[n,:] = relu(h2+b_gcn)@W3 + b3.  (norm == alpha: deg == 1 identity)
// ---------------------------------------------------------------------------
__global__ __launch_bounds__(256) void k_h2f(
    const u32* __restrict__ rowptr, const uint4* __restrict__ erec,
    const float* __restrict__ den_g, const uint2* __restrict__ hg8,
    const float* __restrict__ bgcn, const float* __restrict__ W3,
    const float* __restrict__ b3,
    float* __restrict__ out_alpha, float* __restrict__ out)
{
    int n = (blockIdx.x << 2) + (threadIdx.x >> 6);
    int lane = threadIdx.x & 63;
    int g = lane >> 4;
    int gl = lane & 15;

    float w30[8], w31[8], bg[8];
#pragma unroll
    for (int j = 0; j < 8; ++j) {
        int c = 16 * j + gl;
        w30[j] = W3[2 * c];
        w31[j] = W3[2 * c + 1];
        bg[j]  = bgcn[c];
    }

    float dn = den_g[n];
    float rden = (dn > 1e-30f) ? 1.f / dn : 0.f;
    u32 p0 = rowptr[n], p1 = rowptr[n + 1];
    float acc[8] = {0.f, 0.f, 0.f, 0.f, 0.f, 0.f, 0.f, 0.f};

    for (u32 p = p0 + g; p < p1; p += 4) {
        uint4 er = erec[p];
        float a = __uint_as_float(er.w) * rden;
        if (gl == 0) out_alpha[er.z] = a;
        uint2 w = hg8[(size_t)er.x * 16 + gl];
        f32x2 d0 = unpk_fp8<false>(w.x), d1 = unpk_fp8<true>(w.x);
        f32x2 d2 = unpk_fp8<false>(w.y), d3 = unpk_fp8<true>(w.y);
        acc[0] += a * d0.x; acc[1] += a * d0.y;
        acc[2] += a * d1.x; acc[3] += a * d1.y;
        acc[4] += a * d2.x; acc[5] += a * d2.y;
        acc[6] += a * d3.x; acc[7] += a * d3.y;
    }
#pragma unroll
    for (int j = 0; j < 8; ++j) {
        acc[j] += __shfl_xor(acc[j], 16, 64);
        acc[j] += __shfl_xor(acc[j], 32, 64);
    }
    float o0 = 0.f, o1 = 0.f;
#pragma unroll
    for (int j = 0; j < 8; ++j) {
        float v = acc[j] + bg[j];
        v = v > 0.f ? v : 0.f;
        o0 += v * w30[j];
        o1 += v * w31[j];
    }
    o0 += __shfl_xor(o0, 1, 64); o1 += __shfl_xor(o1, 1, 64);
    o0 += __shfl_xor(o0, 2, 64); o1 += __shfl_xor(o1, 2, 64);
    o0 += __shfl_xor(o0, 4, 64); o1 += __shfl_xor(o1, 4, 64);
    o0 += __shfl_xor(o0, 8, 64); o1 += __shfl_xor(o1, 8, 64);
    if (lane == 0) {
        out[n * 2]     = o0 + b3[0];
        out[n * 2 + 1] = o1 + b3[1];
    }
}

// ---------------------------------------------------------------------------
extern "C" void kernel_launch(void* const* d_in, const int* in_sizes, int n_in,
                              void* d_out, int out_size, void* d_ws, size_t ws_size,
                              hipStream_t stream)
{
    const float* x    = (const float*)d_in[0];
    const int*   ei   = (const int*)d_in[1];
    const float* ew   = (const float*)d_in[2];
    const float* Wl   = (const float*)d_in[3];
    const float* bl   = (const float*)d_in[4];
    const float* Wr   = (const float*)d_in[5];
    const float* br   = (const float*)d_in[6];
    const float* We   = (const float*)d_in[7];
    const float* att  = (const float*)d_in[8];
    const float* bgat = (const float*)d_in[9];
    const float* W2   = (const float*)d_in[10];
    const float* bgcn = (const float*)d_in[11];
    const float* W3   = (const float*)d_in[12];
    const float* b3   = (const float*)d_in[13];

    float* out       = (float*)d_out;          // chunk0: out [N,2] f32
    float* out_idx   = out + 200000;           // chunk1: stack([src,dst]) [2,ET]
    float* out_alpha = out + 200000 + 2 * ET;  // chunk2: alpha [ET,1]

    // workspace (~66.5 MB):
    // xl8 u32[NN*32] (fp8 xl; later hg8 fp8)  | xrh uint2[NN*32] (bf16 xr -> h)
    // | erec uint4[ET] | cnt u32[NN] (later den_g f32) | rowptr[NN+1] | bsum[512]
    u32*   xl8    = (u32*)d_ws;
    uint2* xrh    = (uint2*)(xl8 + (size_t)NN * 32);
    uint4* erec   = (uint4*)(xrh + (size_t)NN * 32);
    u32*   cnt    = (u32*)(erec + ET);
    float* den    = (float*)cnt;               // aliased after scatter
    u32*   rowptr = cnt + NN;
    u32*   bsum   = rowptr + NN + 1;

    const int EB = (ET + 255) / 256;
    const int SB = (NN + 255) / 256;           // 391

    // --- CSR build (+ out_idx) ---
    hipMemsetAsync(cnt, 0, NN * sizeof(u32), stream);
    k_deg<<<EB, 256, 0, stream>>>(ei, cnt);
    k_scanA<<<SB, 256, 0, stream>>>(cnt, bsum);
    k_scanB<<<1, 512, 0, stream>>>(bsum, SB);
    k_scanC<<<SB, 256, 0, stream>>>(cnt, bsum, rowptr);
    hipMemsetAsync(cnt, 0, NN * sizeof(u32), stream);
    k_scatter<<<EB, 256, 0, stream>>>(ei, ew, rowptr, cnt, erec, out_idx);

    // --- projections + fused attention/aggregation ---
    k_pre<<<(NN * 32) / 256, 256, 0, stream>>>(x, Wl, bl, Wr, br, xl8, xrh);
    k_fused<<<NN / 4, 256, 0, stream>>>(rowptr, erec, xl8, We, att, bgat,
                                        (uint4*)xrh, den);

    // --- GCN (MFMA, fp8 out) + fused h2+MLP ---
    k_gemm1<<<512, 256, 0, stream>>>((const u32*)xrh, W2, (uint2*)xl8);
    k_h2f<<<NN / 4, 256, 0, stream>>>(rowptr, erec, den, (const uint2*)xl8,
                                      bgcn, W3, b3, out_alpha, out);
}